// Round 1
// 818.954 us; speedup vs baseline: 1.1009x; 1.1009x over previous
//
#include <hip/hip_runtime.h>
#include <hip/hip_bf16.h>

// Problem constants
#define BB 4
#define NN 4096
#define DD 2048
#define HH 16
#define DK 128
#define MTOK (BB * NN)       // 16384 tokens
#define QKVW (3 * DD)        // 6144

typedef __bf16 bf16x8 __attribute__((ext_vector_type(8)));
typedef __bf16 bf16x4 __attribute__((ext_vector_type(4)));
typedef float f32x4 __attribute__((ext_vector_type(4)));

// ---- async global -> LDS, 16 bytes per lane (lane lands at ldsbase + lane*16) ----
__device__ __forceinline__ void gload16(const __bf16* g, __bf16* lds_wave_uniform_base) {
    __builtin_amdgcn_global_load_lds(
        (const __attribute__((address_space(1))) void*)g,
        (__attribute__((address_space(3))) void*)lds_wave_uniform_base,
        16, 0, 0);
}

// ------------------------------------------------------------------
// X fp32 -> bf16 elementwise convert (vectorized float4 -> bf16x4)
// ------------------------------------------------------------------
__global__ __launch_bounds__(256) void xconv_kernel(const float* __restrict__ X,
                                                    __bf16* __restrict__ Xb, int n4) {
    int i = blockIdx.x * blockDim.x + threadIdx.x;
    if (i < n4) {
        float4 v = reinterpret_cast<const float4*>(X)[i];
        bf16x4 o;
        o[0] = (__bf16)v.x; o[1] = (__bf16)v.y; o[2] = (__bf16)v.z; o[3] = (__bf16)v.w;
        reinterpret_cast<bf16x4*>(Xb)[i] = o;
    }
}

// ------------------------------------------------------------------
// Weight transpose-convert: W (K=2048, N=2048) fp32 row-major -> Wt (N, K) bf16
// ------------------------------------------------------------------
__global__ __launch_bounds__(256) void wconv_kernel(const float* __restrict__ W0,
                                                    const float* __restrict__ W1,
                                                    const float* __restrict__ W2,
                                                    const float* __restrict__ W3,
                                                    __bf16* __restrict__ Wcat,
                                                    __bf16* __restrict__ Wo_t) {
    __shared__ float tile[32][33];
    const int w = blockIdx.z;
    const float* W = (w == 0) ? W0 : (w == 1) ? W1 : (w == 2) ? W2 : W3;
    __bf16* dst = (w < 3) ? (Wcat + (size_t)w * DD * DD) : Wo_t;
    const int tx = threadIdx.x, ty = threadIdx.y;     // block (32, 8)
    const int n0 = blockIdx.x * 32, k0 = blockIdx.y * 32;
#pragma unroll
    for (int j = 0; j < 32; j += 8)
        tile[ty + j][tx] = W[(size_t)(k0 + ty + j) * DD + n0 + tx];
    __syncthreads();
#pragma unroll
    for (int j = 0; j < 32; j += 8)
        dst[(size_t)(n0 + ty + j) * DD + k0 + tx] = (__bf16)tile[tx][ty + j];
}

// ------------------------------------------------------------------
// 256x256 8-phase GEMM (m201 template, plain HIP): C[M,N] = A[M,K] @ Bt[N,K]^T.
// 512 thr = 8 waves (2M x 4N); per-wave C = 128x64 via 8x4 grid of 16x16x32
// bf16 MFMA fragments (acc = 128 VGPR). LDS 128 KiB:
//   lds[2 dbuf][4 granules: A_k0, A_k1, B_k0, B_k1][16 KiB].
// Granule = 256 rows x 32 k bf16, organized as 16 subtiles (16 rows x 32 k,
// 1024 B) with st_16x32 swizzle: stored_kbyte = kbyte ^ ((row&8) ? 32 : 0).
// global_load_lds writes LINEARLY (base + lane*16); the swizzle is realized by
// pre-swizzling the per-lane GLOBAL source address, and reads apply the same
// XOR (rule 21: both-sides-or-neither).
//
// Phases per K-tile T (kh = 32-wide K slice, mh = M-half of the wave tile):
//   p0 (mh0,kh0): ds 8 (A mi0-3 k0 + B k0), stage B_k0(T+1)
//   p1 (mh0,kh1): ds 8 (A mi0-3 k1 + B k1), stage A_k1(T+1)
//   p2 (mh1,kh0): ds 4 (A mi4-7 k0),        stage B_k1(T+1)   [B k0 regs reused]
//   p3 (mh1,kh1): ds 4 (A mi4-7 k1),        stage A_k0(T+2)   [slot freed at p2]
// Each phase: reads+stage | s_barrier | sched_barrier | setprio(1) | 16 MFMA |
// setprio(0) | s_barrier.  Counted vmcnt(2) ONCE per K-tile at p3 (T4): the
// newest granule (A_k0(T+2)) stays in flight across the tile boundary;
// everything tile T+1 reads is guaranteed landed. Issue->first-use distance is
// 3-5 phases. Drain vmcnt(0) only for the last two tiles (epilogue).
// Requires NT = K/64 even (K=2048 -> 32) and M,N % 256 == 0.
// ------------------------------------------------------------------
template <typename OutT>
__global__ __launch_bounds__(512, 2) void gemm256(const __bf16* __restrict__ A, int lda,
                                                  const __bf16* __restrict__ Bt, int ldb,
                                                  OutT* __restrict__ C, int ldc, int K) {
    __shared__ __align__(16) __bf16 lds[2][4][8192];
    const int NT = K >> 6;

    const int tid = threadIdx.x;
    const int wave = tid >> 6, lane = tid & 63;
    const int wm = wave >> 2, wn = wave & 3;

    // XCD-aware block swizzle (grids here are multiples of 8: 1536 / 512 blocks)
    const int nbx = gridDim.x;
    const int nwg = nbx * gridDim.y;
    int flat = blockIdx.y * nbx + blockIdx.x;
    flat = (flat & 7) * (nwg >> 3) + (flat >> 3);
    const size_t blockM = (size_t)(flat / nbx) * 256;
    const size_t blockN = (size_t)(flat % nbx) * 256;

    // staging: lane l of segment rg loads global (row = rg*16 + (l>>2),
    // k = kel) so the linear LDS write (lane*16) lands st_16x32-swizzled.
    const int kel = ((((lane >> 1) ^ (lane >> 5)) & 1) << 4) + ((lane & 1) << 3);
    const __bf16* sA = A + (blockM + (size_t)(lane >> 2)) * lda + kel;
    const __bf16* sB = Bt + (blockN + (size_t)(lane >> 2)) * ldb + kel;

    // swizzled per-lane read offset within a granule subtile (bytes):
    // row r16 = lane&15, chunk g = lane>>4, XOR 32 for rows 8..15.
    const int ldsOff = (lane & 15) * 64 + (((lane >> 4) * 16) ^ (((lane >> 3) & 1) << 5));
    const int aOff = wm * 8192 + ldsOff;   // wave's A rowgroup base (wm*8 subtiles)
    const int bOff = wn * 4096 + ldsOff;   // wave's B rowgroup base (wn*4 subtiles)

#define STAGE_A(t, khc)                                                                   \
    do {                                                                                  \
        const int _k = (t) * 64 + (khc) * 32;                                             \
        gload16(sA + (size_t)(wave * 32) * lda + _k,                                      \
                &lds[(t) & 1][(khc)][wave * 1024]);                                       \
        gload16(sA + (size_t)(wave * 32 + 16) * lda + _k,                                 \
                &lds[(t) & 1][(khc)][wave * 1024 + 512]);                                 \
    } while (0)
#define STAGE_B(t, khc)                                                                   \
    do {                                                                                  \
        const int _k = (t) * 64 + (khc) * 32;                                             \
        gload16(sB + (size_t)(wave * 32) * ldb + _k,                                      \
                &lds[(t) & 1][2 + (khc)][wave * 1024]);                                   \
        gload16(sB + (size_t)(wave * 32 + 16) * ldb + _k,                                 \
                &lds[(t) & 1][2 + (khc)][wave * 1024 + 512]);                             \
    } while (0)

    f32x4 acc[8][4] = {};

    // prologue: tile 0 fully + A_k0 of tile 1 (10 loads); keep newest granule in flight
    STAGE_A(0, 0); STAGE_B(0, 0); STAGE_A(0, 1); STAGE_B(0, 1);
    STAGE_A(1, 0);
    asm volatile("s_waitcnt vmcnt(2)" ::: "memory");
    asm volatile("s_barrier" ::: "memory");

#pragma unroll 2
    for (int T = 0; T < NT; ++T) {
        const int b = T & 1;
        bf16x8 bk0[4], bk1[4];

        // ---- p0: mh0, kh0 -- load A(k0) lo + B(k0); stage B_k0(T+1) ----
        {
            bf16x8 af[4];
            const char* Ag = (const char*)&lds[b][0][0];
            const char* Bg = (const char*)&lds[b][2][0];
#pragma unroll
            for (int mi = 0; mi < 4; ++mi)
                af[mi] = *(const bf16x8*)(Ag + aOff + mi * 1024);
#pragma unroll
            for (int ni = 0; ni < 4; ++ni)
                bk0[ni] = *(const bf16x8*)(Bg + bOff + ni * 1024);
            if (T + 1 < NT) STAGE_B(T + 1, 0);
            asm volatile("s_barrier" ::: "memory");
            __builtin_amdgcn_sched_barrier(0);
            __builtin_amdgcn_s_setprio(1);
#pragma unroll
            for (int mi = 0; mi < 4; ++mi)
#pragma unroll
                for (int ni = 0; ni < 4; ++ni)
                    acc[mi][ni] = __builtin_amdgcn_mfma_f32_16x16x32_bf16(
                        af[mi], bk0[ni], acc[mi][ni], 0, 0, 0);
            __builtin_amdgcn_sched_barrier(0);
            __builtin_amdgcn_s_setprio(0);
            asm volatile("s_barrier" ::: "memory");
        }

        // ---- p1: mh0, kh1 -- load A(k1) lo + B(k1); stage A_k1(T+1) ----
        {
            bf16x8 af[4];
            const char* Ag = (const char*)&lds[b][1][0];
            const char* Bg = (const char*)&lds[b][3][0];
#pragma unroll
            for (int mi = 0; mi < 4; ++mi)
                af[mi] = *(const bf16x8*)(Ag + aOff + mi * 1024);
#pragma unroll
            for (int ni = 0; ni < 4; ++ni)
                bk1[ni] = *(const bf16x8*)(Bg + bOff + ni * 1024);
            if (T + 1 < NT) STAGE_A(T + 1, 1);
            asm volatile("s_barrier" ::: "memory");
            __builtin_amdgcn_sched_barrier(0);
            __builtin_amdgcn_s_setprio(1);
#pragma unroll
            for (int mi = 0; mi < 4; ++mi)
#pragma unroll
                for (int ni = 0; ni < 4; ++ni)
                    acc[mi][ni] = __builtin_amdgcn_mfma_f32_16x16x32_bf16(
                        af[mi], bk1[ni], acc[mi][ni], 0, 0, 0);
            __builtin_amdgcn_sched_barrier(0);
            __builtin_amdgcn_s_setprio(0);
            asm volatile("s_barrier" ::: "memory");
        }

        // ---- p2: mh1, kh0 -- load A(k0) hi (B k0 regs reused); stage B_k1(T+1) ----
        {
            bf16x8 af[4];
            const char* Ag = (const char*)&lds[b][0][0];
#pragma unroll
            for (int mi = 0; mi < 4; ++mi)
                af[mi] = *(const bf16x8*)(Ag + aOff + 4096 + mi * 1024);
            if (T + 1 < NT) STAGE_B(T + 1, 1);
            asm volatile("s_barrier" ::: "memory");
            __builtin_amdgcn_sched_barrier(0);
            __builtin_amdgcn_s_setprio(1);
#pragma unroll
            for (int mi = 0; mi < 4; ++mi)
#pragma unroll
                for (int ni = 0; ni < 4; ++ni)
                    acc[4 + mi][ni] = __builtin_amdgcn_mfma_f32_16x16x32_bf16(
                        af[mi], bk0[ni], acc[4 + mi][ni], 0, 0, 0);
            __builtin_amdgcn_sched_barrier(0);
            __builtin_amdgcn_s_setprio(0);
            asm volatile("s_barrier" ::: "memory");
        }

        // ---- p3: mh1, kh1 -- load A(k1) hi (B k1 regs reused); stage A_k0(T+2)
        //      (slot lds[b][0] freed by p2's post-MFMA barrier); counted vmcnt ----
        {
            bf16x8 af[4];
            const char* Ag = (const char*)&lds[b][1][0];
#pragma unroll
            for (int mi = 0; mi < 4; ++mi)
                af[mi] = *(const bf16x8*)(Ag + aOff + 4096 + mi * 1024);
            if (T + 2 < NT) STAGE_A(T + 2, 0);
            asm volatile("s_barrier" ::: "memory");
            __builtin_amdgcn_sched_barrier(0);
            __builtin_amdgcn_s_setprio(1);
#pragma unroll
            for (int mi = 0; mi < 4; ++mi)
#pragma unroll
                for (int ni = 0; ni < 4; ++ni)
                    acc[4 + mi][ni] = __builtin_amdgcn_mfma_f32_16x16x32_bf16(
                        af[mi], bk1[ni], acc[4 + mi][ni], 0, 0, 0);
            __builtin_amdgcn_sched_barrier(0);
            __builtin_amdgcn_s_setprio(0);
            if (T + 2 < NT) asm volatile("s_waitcnt vmcnt(2)" ::: "memory");
            else            asm volatile("s_waitcnt vmcnt(0)" ::: "memory");
            asm volatile("s_barrier" ::: "memory");
        }
    }
#undef STAGE_A
#undef STAGE_B

    // epilogue: C/D layout col = lane&15, row = (lane>>4)*4 + reg
    const int rEp = (lane >> 4) * 4;
    const int cEp = lane & 15;
#pragma unroll
    for (int mi = 0; mi < 8; ++mi) {
        const size_t row0 = blockM + wm * 128 + mi * 16 + rEp;
#pragma unroll
        for (int ni = 0; ni < 4; ++ni) {
            const size_t col = blockN + wn * 64 + ni * 16 + cEp;
#pragma unroll
            for (int r = 0; r < 4; ++r)
                C[(row0 + r) * (size_t)ldc + col] = (OutT)acc[mi][ni][r];
        }
    }
}

// ------------------------------------------------------------------
// Per-token attention. QKV rows: [q(2048) | k(2048) | v(2048)], bf16.
// One wave per token. scores = q @ k^T via 4 MFMAs (16x16x128), scores->LDS,
// o = scores @ v on VALU (fp32 acc). O written bf16 to COMPACT buffer Ob
// (lda = 2048) for the output GEMM's A-side locality.
// ------------------------------------------------------------------
__global__ __launch_bounds__(256) void attn_kernel(const __bf16* __restrict__ qkv,
                                                   __bf16* __restrict__ Ob) {
    __shared__ float sc[4][16][17];   // +1 pad
    const int tid = threadIdx.x;
    const int wave = tid >> 6;
    const int lane = tid & 63;
    const int t = lane & 15;
    const int quad = lane >> 4;
    const size_t token = (size_t)blockIdx.x * 4 + wave;
    const __bf16* row = qkv + token * QKVW;
    __bf16* orow = Ob + token * DD;

    // scores: A = q (M=16 heads x K=128), B-frag = k[n=t][k-dim] (contiguous)
    f32x4 s = (f32x4){0.f, 0.f, 0.f, 0.f};
#pragma unroll
    for (int ks = 0; ks < 4; ++ks) {
        bf16x8 a = *reinterpret_cast<const bf16x8*>(row + t * DK + ks * 32 + quad * 8);
        bf16x8 b = *reinterpret_cast<const bf16x8*>(row + DD + t * DK + ks * 32 + quad * 8);
        s = __builtin_amdgcn_mfma_f32_16x16x32_bf16(a, b, s, 0, 0, 0);
    }
#pragma unroll
    for (int i = 0; i < 4; ++i) sc[wave][quad * 4 + i][t] = s[i];  // s[h=quad*4+i][j=t]
    __syncthreads();

    // o[h][d] = sum_j s[h][j] * v[j][d]; lane covers heads {quad,quad+4,quad+8,quad+12},
    // d = t*8 .. t*8+7
    const int d0 = t * 8;
    float oa[4][8];
#pragma unroll
    for (int i = 0; i < 4; ++i)
#pragma unroll
        for (int e = 0; e < 8; ++e) oa[i][e] = 0.f;

#pragma unroll
    for (int j = 0; j < 16; ++j) {
        bf16x8 v8 = *reinterpret_cast<const bf16x8*>(row + 2 * DD + j * DK + d0);
        float vf[8];
#pragma unroll
        for (int e = 0; e < 8; ++e) vf[e] = (float)v8[e];
#pragma unroll
        for (int i = 0; i < 4; ++i) {
            const float sj = sc[wave][quad + 4 * i][j];
#pragma unroll
            for (int e = 0; e < 8; ++e) oa[i][e] += sj * vf[e];
        }
    }
#pragma unroll
    for (int i = 0; i < 4; ++i) {
        bf16x8 o8;
#pragma unroll
        for (int e = 0; e < 8; ++e) o8[e] = (__bf16)oa[i][e];
        *reinterpret_cast<bf16x8*>(orow + (quad + 4 * i) * DK + d0) = o8;
    }
}

// ------------------------------------------------------------------
extern "C" void kernel_launch(void* const* d_in, const int* in_sizes, int n_in,
                              void* d_out, int out_size, void* d_ws, size_t ws_size,
                              hipStream_t stream) {
    const float* X  = (const float*)d_in[0];
    const float* Wq = (const float*)d_in[1];
    const float* Wk = (const float*)d_in[2];
    const float* Wv = (const float*)d_in[3];
    const float* Wo = (const float*)d_in[4];
    float* out = (float*)d_out;

    // workspace layout (bf16): [Wcat_t 3*D*D][Wo_t D*D][Xb M*D][QKV M*3D] = 302 MB
    // Xb doubles as the attention-output buffer Ob (Xb dead after QKV GEMM).
    char* ws = (char*)d_ws;
    __bf16* Wcat = (__bf16*)ws;
    __bf16* Wo_t = (__bf16*)(ws + (size_t)3 * DD * DD * 2);
    __bf16* Xb   = (__bf16*)(ws + (size_t)4 * DD * DD * 2);
    __bf16* QKV  = (__bf16*)(ws + (size_t)4 * DD * DD * 2 + (size_t)MTOK * DD * 2);
    __bf16* Ob   = Xb;

    // 1) X -> bf16
    const int n4 = MTOK * DD / 4;
    xconv_kernel<<<(n4 + 255) / 256, 256, 0, stream>>>(X, Xb, n4);

    // 2) weights -> bf16, transposed to (N, K)
    wconv_kernel<<<dim3(DD / 32, DD / 32, 4), dim3(32, 8), 0, stream>>>(
        Wq, Wk, Wv, Wo, Wcat, Wo_t);

    // 3) QKV = Xb @ [Wq|Wk|Wv]  (M=16384, N=6144, K=2048), bf16 out
    gemm256<__bf16><<<dim3(QKVW / 256, MTOK / 256), 512, 0, stream>>>(
        Xb, DD, Wcat, DD, QKV, QKVW, DD);

    // 4) per-token attention -> compact Ob (overwrites Xb region)
    attn_kernel<<<MTOK / 4, 256, 0, stream>>>(QKV, Ob);

    // 5) out = Ob @ Wo  (M=16384, N=2048, K=2048), fp32 out
    gemm256<float><<<dim3(DD / 256, MTOK / 256), 512, 0, stream>>>(
        Ob, DD, Wo_t, DD, out, DD, DD);
}

// Round 2
// 799.765 us; speedup vs baseline: 1.1273x; 1.0240x over previous
//
#include <hip/hip_runtime.h>
#include <hip/hip_bf16.h>

// Problem constants
#define BB 4
#define NN 4096
#define DD 2048
#define HH 16
#define DK 128
#define MTOK (BB * NN)       // 16384 tokens
#define QKVW (3 * DD)        // 6144

typedef __bf16 bf16x8 __attribute__((ext_vector_type(8)));
typedef __bf16 bf16x4 __attribute__((ext_vector_type(4)));
typedef float f32x4 __attribute__((ext_vector_type(4)));

// ---- async global -> LDS, 16 bytes per lane (lane lands at ldsbase + lane*16) ----
__device__ __forceinline__ void gload16(const __bf16* g, __bf16* lds_wave_uniform_base) {
    __builtin_amdgcn_global_load_lds(
        (const __attribute__((address_space(1))) void*)g,
        (__attribute__((address_space(3))) void*)lds_wave_uniform_base,
        16, 0, 0);
}

// ------------------------------------------------------------------
// X fp32 -> bf16 elementwise convert (vectorized float4 -> bf16x4)
// ------------------------------------------------------------------
__global__ __launch_bounds__(256) void xconv_kernel(const float* __restrict__ X,
                                                    __bf16* __restrict__ Xb, int n4) {
    int i = blockIdx.x * blockDim.x + threadIdx.x;
    if (i < n4) {
        float4 v = reinterpret_cast<const float4*>(X)[i];
        bf16x4 o;
        o[0] = (__bf16)v.x; o[1] = (__bf16)v.y; o[2] = (__bf16)v.z; o[3] = (__bf16)v.w;
        reinterpret_cast<bf16x4*>(Xb)[i] = o;
    }
}

// ------------------------------------------------------------------
// Weight transpose-convert: W (K=2048, N=2048) fp32 row-major -> Wt (N, K) bf16
// ------------------------------------------------------------------
__global__ __launch_bounds__(256) void wconv_kernel(const float* __restrict__ W0,
                                                    const float* __restrict__ W1,
                                                    const float* __restrict__ W2,
                                                    const float* __restrict__ W3,
                                                    __bf16* __restrict__ Wcat,
                                                    __bf16* __restrict__ Wo_t) {
    __shared__ float tile[32][33];
    const int w = blockIdx.z;
    const float* W = (w == 0) ? W0 : (w == 1) ? W1 : (w == 2) ? W2 : W3;
    __bf16* dst = (w < 3) ? (Wcat + (size_t)w * DD * DD) : Wo_t;
    const int tx = threadIdx.x, ty = threadIdx.y;     // block (32, 8)
    const int n0 = blockIdx.x * 32, k0 = blockIdx.y * 32;
#pragma unroll
    for (int j = 0; j < 32; j += 8)
        tile[ty + j][tx] = W[(size_t)(k0 + ty + j) * DD + n0 + tx];
    __syncthreads();
#pragma unroll
    for (int j = 0; j < 32; j += 8)
        dst[(size_t)(n0 + ty + j) * DD + k0 + tx] = (__bf16)tile[tx][ty + j];
}

// ------------------------------------------------------------------
// 256x256 8-phase GEMM (m201 template, plain HIP): C[M,N] = A[M,K] @ Bt[N,K]^T.
// 512 thr = 8 waves (2M x 4N); per-wave C = 128x64 via 8x4 grid of 16x16x32
// bf16 MFMA fragments (acc = 128 regs). LDS 128 KiB:
//   lds[2 dbuf][4 granules: A_k0, A_k1, B_k0, B_k1][16 KiB].
// Granule = 256 rows x 32 k bf16, 16 subtiles (16 rows x 32 k, 1024 B) with
// st_16x32 swizzle: stored_kbyte = kbyte ^ ((row&8) ? 32 : 0). global_load_lds
// writes LINEARLY; the swizzle is realized by pre-swizzling the per-lane GLOBAL
// source address, reads apply the same XOR (rule 21: both-sides-or-neither).
//
// DEEP-PIPELINE stage schedule (r1 fix: old p2-staged granule was waited one
// phase after issue -> ~50% MfmaUtil stall; now youngest-waited granule has a
// 3-phase issue->wait distance, B granules 7 phases). Slot liveness with the
// 2-buffer LDS permits 2-tiles-ahead staging for B and A_k0:
//   p0 (mh0,kh0): ds 8 (A mi0-3 k0 + B k0), stage A_k1(T+1)  [slot freed T-1 p3]
//   p1 (mh0,kh1): ds 8 (A mi0-3 k1 + B k1), stage B_k0(T+2)  [slot's last read = T p0]
//   p2 (mh1,kh0): ds 4 (A mi4-7 k0),        stage B_k1(T+2)  [last read = T p1]
//   p3 (mh1,kh1): ds 4 (A mi4-7 k1),        stage A_k0(T+2)  [last read = T p2]
// One counted vmcnt(6) per K-tile at p3 (retain the 3 granules staged at
// p1/p2/p3 = 6 loads, m201's value): everything tile T+1 reads has landed, and
// the youngest load waited on (A_k1(T+1), issued T p0) had 3 phases in flight.
// Drain vmcnt(0) only when T+2 >= NT (last two tiles).
// Requires NT = K/64 >= 3 and M,N % 256 == 0.
// ------------------------------------------------------------------
template <typename OutT>
__global__ __launch_bounds__(512, 2) void gemm256(const __bf16* __restrict__ A, int lda,
                                                  const __bf16* __restrict__ Bt, int ldb,
                                                  OutT* __restrict__ C, int ldc, int K) {
    __shared__ __align__(16) __bf16 lds[2][4][8192];
    const int NT = K >> 6;

    const int tid = threadIdx.x;
    const int wave = tid >> 6, lane = tid & 63;
    const int wm = wave >> 2, wn = wave & 3;

    // XCD-aware block swizzle (grids here are multiples of 8: 1536 / 512 blocks)
    const int nbx = gridDim.x;
    const int nwg = nbx * gridDim.y;
    int flat = blockIdx.y * nbx + blockIdx.x;
    flat = (flat & 7) * (nwg >> 3) + (flat >> 3);
    const size_t blockM = (size_t)(flat / nbx) * 256;
    const size_t blockN = (size_t)(flat % nbx) * 256;

    // staging: lane l of segment rg loads global (row = rg*16 + (l>>2),
    // k = kel) so the linear LDS write (lane*16) lands st_16x32-swizzled.
    const int kel = ((((lane >> 1) ^ (lane >> 5)) & 1) << 4) + ((lane & 1) << 3);
    const __bf16* sA = A + (blockM + (size_t)(lane >> 2)) * lda + kel;
    const __bf16* sB = Bt + (blockN + (size_t)(lane >> 2)) * ldb + kel;

    // swizzled per-lane read offset within a granule subtile (bytes):
    // row r16 = lane&15, chunk g = lane>>4, XOR 32 for rows 8..15.
    const int ldsOff = (lane & 15) * 64 + (((lane >> 4) * 16) ^ (((lane >> 3) & 1) << 5));
    const int aOff = wm * 8192 + ldsOff;   // wave's A rowgroup base (wm*8 subtiles)
    const int bOff = wn * 4096 + ldsOff;   // wave's B rowgroup base (wn*4 subtiles)

#define STAGE_A(t, khc)                                                                   \
    do {                                                                                  \
        const int _k = (t) * 64 + (khc) * 32;                                             \
        gload16(sA + (size_t)(wave * 32) * lda + _k,                                      \
                &lds[(t) & 1][(khc)][wave * 1024]);                                       \
        gload16(sA + (size_t)(wave * 32 + 16) * lda + _k,                                 \
                &lds[(t) & 1][(khc)][wave * 1024 + 512]);                                 \
    } while (0)
#define STAGE_B(t, khc)                                                                   \
    do {                                                                                  \
        const int _k = (t) * 64 + (khc) * 32;                                             \
        gload16(sB + (size_t)(wave * 32) * ldb + _k,                                      \
                &lds[(t) & 1][2 + (khc)][wave * 1024]);                                   \
        gload16(sB + (size_t)(wave * 32 + 16) * ldb + _k,                                 \
                &lds[(t) & 1][2 + (khc)][wave * 1024 + 512]);                             \
    } while (0)

    f32x4 acc[8][4] = {};

    // prologue: tile 0 complete + tile 1's {B_k0, B_k1, A_k0} (the granules the
    // steady-state schedule would have staged during "tile -1"). 7 granules =
    // 14 loads; vmcnt(6) retains the 3 tile-1 granules in flight.
    STAGE_A(0, 0); STAGE_B(0, 0); STAGE_A(0, 1); STAGE_B(0, 1);
    STAGE_B(1, 0); STAGE_B(1, 1); STAGE_A(1, 0);
    asm volatile("s_waitcnt vmcnt(6)" ::: "memory");
    asm volatile("s_barrier" ::: "memory");

#pragma unroll 2
    for (int T = 0; T < NT; ++T) {
        const int b = T & 1;
        bf16x8 bk0[4], bk1[4];

        // ---- p0: mh0, kh0 -- load A(k0) lo + B(k0); stage A_k1(T+1) ----
        {
            bf16x8 af[4];
            const char* Ag = (const char*)&lds[b][0][0];
            const char* Bg = (const char*)&lds[b][2][0];
#pragma unroll
            for (int mi = 0; mi < 4; ++mi)
                af[mi] = *(const bf16x8*)(Ag + aOff + mi * 1024);
#pragma unroll
            for (int ni = 0; ni < 4; ++ni)
                bk0[ni] = *(const bf16x8*)(Bg + bOff + ni * 1024);
            if (T + 1 < NT) STAGE_A(T + 1, 1);
            asm volatile("s_barrier" ::: "memory");
            __builtin_amdgcn_sched_barrier(0);
            __builtin_amdgcn_s_setprio(1);
#pragma unroll
            for (int mi = 0; mi < 4; ++mi)
#pragma unroll
                for (int ni = 0; ni < 4; ++ni)
                    acc[mi][ni] = __builtin_amdgcn_mfma_f32_16x16x32_bf16(
                        af[mi], bk0[ni], acc[mi][ni], 0, 0, 0);
            __builtin_amdgcn_sched_barrier(0);
            __builtin_amdgcn_s_setprio(0);
            asm volatile("s_barrier" ::: "memory");
        }

        // ---- p1: mh0, kh1 -- load A(k1) lo + B(k1); stage B_k0(T+2)
        //      (slot lds[b][2]'s only read this tile was p0) ----
        {
            bf16x8 af[4];
            const char* Ag = (const char*)&lds[b][1][0];
            const char* Bg = (const char*)&lds[b][3][0];
#pragma unroll
            for (int mi = 0; mi < 4; ++mi)
                af[mi] = *(const bf16x8*)(Ag + aOff + mi * 1024);
#pragma unroll
            for (int ni = 0; ni < 4; ++ni)
                bk1[ni] = *(const bf16x8*)(Bg + bOff + ni * 1024);
            if (T + 2 < NT) STAGE_B(T + 2, 0);
            asm volatile("s_barrier" ::: "memory");
            __builtin_amdgcn_sched_barrier(0);
            __builtin_amdgcn_s_setprio(1);
#pragma unroll
            for (int mi = 0; mi < 4; ++mi)
#pragma unroll
                for (int ni = 0; ni < 4; ++ni)
                    acc[mi][ni] = __builtin_amdgcn_mfma_f32_16x16x32_bf16(
                        af[mi], bk1[ni], acc[mi][ni], 0, 0, 0);
            __builtin_amdgcn_sched_barrier(0);
            __builtin_amdgcn_s_setprio(0);
            asm volatile("s_barrier" ::: "memory");
        }

        // ---- p2: mh1, kh0 -- load A(k0) hi (B k0 regs reused); stage B_k1(T+2)
        //      (slot lds[b][3]'s last read was p1) ----
        {
            bf16x8 af[4];
            const char* Ag = (const char*)&lds[b][0][0];
#pragma unroll
            for (int mi = 0; mi < 4; ++mi)
                af[mi] = *(const bf16x8*)(Ag + aOff + 4096 + mi * 1024);
            if (T + 2 < NT) STAGE_B(T + 2, 1);
            asm volatile("s_barrier" ::: "memory");
            __builtin_amdgcn_sched_barrier(0);
            __builtin_amdgcn_s_setprio(1);
#pragma unroll
            for (int mi = 0; mi < 4; ++mi)
#pragma unroll
                for (int ni = 0; ni < 4; ++ni)
                    acc[4 + mi][ni] = __builtin_amdgcn_mfma_f32_16x16x32_bf16(
                        af[mi], bk0[ni], acc[4 + mi][ni], 0, 0, 0);
            __builtin_amdgcn_sched_barrier(0);
            __builtin_amdgcn_s_setprio(0);
            asm volatile("s_barrier" ::: "memory");
        }

        // ---- p3: mh1, kh1 -- load A(k1) hi (B k1 regs reused); stage A_k0(T+2)
        //      (slot lds[b][0]'s last read was p2); counted vmcnt(6) ----
        {
            bf16x8 af[4];
            const char* Ag = (const char*)&lds[b][1][0];
#pragma unroll
            for (int mi = 0; mi < 4; ++mi)
                af[mi] = *(const bf16x8*)(Ag + aOff + 4096 + mi * 1024);
            if (T + 2 < NT) STAGE_A(T + 2, 0);
            asm volatile("s_barrier" ::: "memory");
            __builtin_amdgcn_sched_barrier(0);
            __builtin_amdgcn_s_setprio(1);
#pragma unroll
            for (int mi = 0; mi < 4; ++mi)
#pragma unroll
                for (int ni = 0; ni < 4; ++ni)
                    acc[4 + mi][ni] = __builtin_amdgcn_mfma_f32_16x16x32_bf16(
                        af[mi], bk1[ni], acc[4 + mi][ni], 0, 0, 0);
            __builtin_amdgcn_sched_barrier(0);
            __builtin_amdgcn_s_setprio(0);
            if (T + 2 < NT) asm volatile("s_waitcnt vmcnt(6)" ::: "memory");
            else            asm volatile("s_waitcnt vmcnt(0)" ::: "memory");
            asm volatile("s_barrier" ::: "memory");
        }
    }
#undef STAGE_A
#undef STAGE_B

    // epilogue: C/D layout col = lane&15, row = (lane>>4)*4 + reg
    const int rEp = (lane >> 4) * 4;
    const int cEp = lane & 15;
#pragma unroll
    for (int mi = 0; mi < 8; ++mi) {
        const size_t row0 = blockM + wm * 128 + mi * 16 + rEp;
#pragma unroll
        for (int ni = 0; ni < 4; ++ni) {
            const size_t col = blockN + wn * 64 + ni * 16 + cEp;
#pragma unroll
            for (int r = 0; r < 4; ++r)
                C[(row0 + r) * (size_t)ldc + col] = (OutT)acc[mi][ni][r];
        }
    }
}

// ------------------------------------------------------------------
// Per-token attention. QKV rows: [q(2048) | k(2048) | v(2048)], bf16.
// One wave per token. scores = q @ k^T via 4 MFMAs (16x16x128), scores->LDS,
// o = scores @ v on VALU (fp32 acc). O written bf16 to COMPACT buffer Ob
// (lda = 2048) for the output GEMM's A-side locality.
// ------------------------------------------------------------------
__global__ __launch_bounds__(256) void attn_kernel(const __bf16* __restrict__ qkv,
                                                   __bf16* __restrict__ Ob) {
    __shared__ float sc[4][16][17];   // +1 pad
    const int tid = threadIdx.x;
    const int wave = tid >> 6;
    const int lane = tid & 63;
    const int t = lane & 15;
    const int quad = lane >> 4;
    const size_t token = (size_t)blockIdx.x * 4 + wave;
    const __bf16* row = qkv + token * QKVW;
    __bf16* orow = Ob + token * DD;

    // scores: A = q (M=16 heads x K=128), B-frag = k[n=t][k-dim] (contiguous)
    f32x4 s = (f32x4){0.f, 0.f, 0.f, 0.f};
#pragma unroll
    for (int ks = 0; ks < 4; ++ks) {
        bf16x8 a = *reinterpret_cast<const bf16x8*>(row + t * DK + ks * 32 + quad * 8);
        bf16x8 b = *reinterpret_cast<const bf16x8*>(row + DD + t * DK + ks * 32 + quad * 8);
        s = __builtin_amdgcn_mfma_f32_16x16x32_bf16(a, b, s, 0, 0, 0);
    }
#pragma unroll
    for (int i = 0; i < 4; ++i) sc[wave][quad * 4 + i][t] = s[i];  // s[h=quad*4+i][j=t]
    __syncthreads();

    // o[h][d] = sum_j s[h][j] * v[j][d]; lane covers heads {quad,quad+4,quad+8,quad+12},
    // d = t*8 .. t*8+7
    const int d0 = t * 8;
    float oa[4][8];
#pragma unroll
    for (int i = 0; i < 4; ++i)
#pragma unroll
        for (int e = 0; e < 8; ++e) oa[i][e] = 0.f;

#pragma unroll
    for (int j = 0; j < 16; ++j) {
        bf16x8 v8 = *reinterpret_cast<const bf16x8*>(row + 2 * DD + j * DK + d0);
        float vf[8];
#pragma unroll
        for (int e = 0; e < 8; ++e) vf[e] = (float)v8[e];
#pragma unroll
        for (int i = 0; i < 4; ++i) {
            const float sj = sc[wave][quad + 4 * i][j];
#pragma unroll
            for (int e = 0; e < 8; ++e) oa[i][e] += sj * vf[e];
        }
    }
#pragma unroll
    for (int i = 0; i < 4; ++i) {
        bf16x8 o8;
#pragma unroll
        for (int e = 0; e < 8; ++e) o8[e] = (__bf16)oa[i][e];
        *reinterpret_cast<bf16x8*>(orow + (quad + 4 * i) * DK + d0) = o8;
    }
}

// ------------------------------------------------------------------
extern "C" void kernel_launch(void* const* d_in, const int* in_sizes, int n_in,
                              void* d_out, int out_size, void* d_ws, size_t ws_size,
                              hipStream_t stream) {
    const float* X  = (const float*)d_in[0];
    const float* Wq = (const float*)d_in[1];
    const float* Wk = (const float*)d_in[2];
    const float* Wv = (const float*)d_in[3];
    const float* Wo = (const float*)d_in[4];
    float* out = (float*)d_out;

    // workspace layout (bf16): [Wcat_t 3*D*D][Wo_t D*D][Xb M*D][QKV M*3D] = 302 MB
    // Xb doubles as the attention-output buffer Ob (Xb dead after QKV GEMM).
    char* ws = (char*)d_ws;
    __bf16* Wcat = (__bf16*)ws;
    __bf16* Wo_t = (__bf16*)(ws + (size_t)3 * DD * DD * 2);
    __bf16* Xb   = (__bf16*)(ws + (size_t)4 * DD * DD * 2);
    __bf16* QKV  = (__bf16*)(ws + (size_t)4 * DD * DD * 2 + (size_t)MTOK * DD * 2);
    __bf16* Ob   = Xb;

    // 1) X -> bf16
    const int n4 = MTOK * DD / 4;
    xconv_kernel<<<(n4 + 255) / 256, 256, 0, stream>>>(X, Xb, n4);

    // 2) weights -> bf16, transposed to (N, K)
    wconv_kernel<<<dim3(DD / 32, DD / 32, 4), dim3(32, 8), 0, stream>>>(
        Wq, Wk, Wv, Wo, Wcat, Wo_t);

    // 3) QKV = Xb @ [Wq|Wk|Wv]  (M=16384, N=6144, K=2048), bf16 out
    gemm256<__bf16><<<dim3(QKVW / 256, MTOK / 256), 512, 0, stream>>>(
        Xb, DD, Wcat, DD, QKV, QKVW, DD);

    // 4) per-token attention -> compact Ob (overwrites Xb region)
    attn_kernel<<<MTOK / 4, 256, 0, stream>>>(QKV, Ob);

    // 5) out = Ob @ Wo  (M=16384, N=2048, K=2048), fp32 out
    gemm256<float><<<dim3(DD / 256, MTOK / 256), 512, 0, stream>>>(
        Ob, DD, Wo_t, DD, out, DD, DD);
}

// Round 3
// 781.549 us; speedup vs baseline: 1.1536x; 1.0233x over previous
//
#include <hip/hip_runtime.h>
#include <hip/hip_bf16.h>

// Problem constants
#define BB 4
#define NN 4096
#define DD 2048
#define HH 16
#define DK 128
#define MTOK (BB * NN)       // 16384 tokens
#define QKVW (3 * DD)        // 6144

typedef __bf16 bf16x8 __attribute__((ext_vector_type(8)));
typedef __bf16 bf16x4 __attribute__((ext_vector_type(4)));
typedef float f32x4 __attribute__((ext_vector_type(4)));

// ---- async global -> LDS, 16 bytes per lane (lane lands at ldsbase + lane*16) ----
__device__ __forceinline__ void gload16(const __bf16* g, __bf16* lds_wave_uniform_base) {
    __builtin_amdgcn_global_load_lds(
        (const __attribute__((address_space(1))) void*)g,
        (__attribute__((address_space(3))) void*)lds_wave_uniform_base,
        16, 0, 0);
}

// ------------------------------------------------------------------
// X fp32 -> bf16 elementwise convert (vectorized float4 -> bf16x4)
// ------------------------------------------------------------------
__global__ __launch_bounds__(256) void xconv_kernel(const float* __restrict__ X,
                                                    __bf16* __restrict__ Xb, int n4) {
    int i = blockIdx.x * blockDim.x + threadIdx.x;
    if (i < n4) {
        float4 v = reinterpret_cast<const float4*>(X)[i];
        bf16x4 o;
        o[0] = (__bf16)v.x; o[1] = (__bf16)v.y; o[2] = (__bf16)v.z; o[3] = (__bf16)v.w;
        reinterpret_cast<bf16x4*>(Xb)[i] = o;
    }
}

// ------------------------------------------------------------------
// Weight transpose-convert: W (K=2048, N=2048) fp32 row-major -> Wt (N, K) bf16
// ------------------------------------------------------------------
__global__ __launch_bounds__(256) void wconv_kernel(const float* __restrict__ W0,
                                                    const float* __restrict__ W1,
                                                    const float* __restrict__ W2,
                                                    const float* __restrict__ W3,
                                                    __bf16* __restrict__ Wcat,
                                                    __bf16* __restrict__ Wo_t) {
    __shared__ float tile[32][33];
    const int w = blockIdx.z;
    const float* W = (w == 0) ? W0 : (w == 1) ? W1 : (w == 2) ? W2 : W3;
    __bf16* dst = (w < 3) ? (Wcat + (size_t)w * DD * DD) : Wo_t;
    const int tx = threadIdx.x, ty = threadIdx.y;     // block (32, 8)
    const int n0 = blockIdx.x * 32, k0 = blockIdx.y * 32;
#pragma unroll
    for (int j = 0; j < 32; j += 8)
        tile[ty + j][tx] = W[(size_t)(k0 + ty + j) * DD + n0 + tx];
    __syncthreads();
#pragma unroll
    for (int j = 0; j < 32; j += 8)
        dst[(size_t)(n0 + ty + j) * DD + k0 + tx] = (__bf16)tile[tx][ty + j];
}

// ------------------------------------------------------------------
// 256x256 8-phase GEMM, r3: READ-HOISTED schedule. C[M,N] = A[M,K] @ Bt[N,K]^T.
// 512 thr = 8 waves (2M x 4N); per-wave C = 128x64 via 8x4 grid of 16x16x32
// bf16 MFMA (acc = 128 regs). LDS 128 KiB: lds[2][4 granules: A_k0,A_k1,B_k0,
// B_k1][16 KiB], granule = 256 rows x 32 k, st_16x32 swizzle via pre-swizzled
// global source (rule 21), reads apply matching XOR. 0 bank conflicts (r1/r2).
//
// r2 post-mortem: reads and MFMAs strictly alternated between barriers ->
// per-tile = MFMA 2483 + LDS 2048 + 8 barriers = 5190 cyc (sum, not max).
// r3 fix (T3's actual mechanism, m196): issue ds_reads 1+ phase before their
// MFMA cluster, gate with counted lgkmcnt (DS retires in-order; cap 15
// respected: 16 issued at p0, 8 at p1). Reads drain DURING the previous MFMA
// burst. This also makes the pre-MFMA barrier redundant -> 4 barriers/tile.
//
//   p0: issue a0,b0,a1,b1 (16 ds_read_b128); stage A_k1(T+1);
//       lgkmcnt(8) [a0,b0 done]; MFMA a0xb0 -> acc[0..3]; barrier
//   p1: issue a2,a3 (8); stage B_k0(T+2); lgkmcnt(8) [a1,b1 done];
//       MFMA a1xb1 -> acc[0..3]; barrier
//   p2: stage B_k1(T+2); lgkmcnt(4) [a2 done]; MFMA a2xb0 -> acc[4..7]; barrier
//   p3: stage A_k0(T+2); lgkmcnt(0); MFMA a3xb1 -> acc[4..7];
//       vmcnt(6) (drain through A_k1(T+1), retain T+2 granules); barrier
//
// Write-after-read safety (each stage target's readers gated before a barrier
// the stager crosses): A_k1(T+1)@p0 -> last read tile T-1 (pre-boundary-bar);
// B_k0(T+2)@p1 -> read by b0 (p0 gate + p0 barrier); B_k1(T+2)@p2 -> b1 (p1
// gate + barrier); A_k0(T+2)@p3 -> a0 (p0) and a2 (p2 gate + barrier). Landing
// safety: tile T+1's reads covered by vmcnt(6)+boundary barrier (per-wave vmcnt
// BEFORE the barrier gives the cross-wave guarantee). NT >= 3, M,N % 256 == 0.
// ------------------------------------------------------------------
template <typename OutT>
__global__ __launch_bounds__(512, 2) void gemm256(const __bf16* __restrict__ A, int lda,
                                                  const __bf16* __restrict__ Bt, int ldb,
                                                  OutT* __restrict__ C, int ldc, int K) {
    __shared__ __align__(16) __bf16 lds[2][4][8192];
    const int NT = K >> 6;

    const int tid = threadIdx.x;
    const int wave = tid >> 6, lane = tid & 63;
    const int wm = wave >> 2, wn = wave & 3;

    // XCD-aware block swizzle (grids here are multiples of 8: 1536 / 512 blocks)
    const int nbx = gridDim.x;
    const int nwg = nbx * gridDim.y;
    int flat = blockIdx.y * nbx + blockIdx.x;
    flat = (flat & 7) * (nwg >> 3) + (flat >> 3);
    const size_t blockM = (size_t)(flat / nbx) * 256;
    const size_t blockN = (size_t)(flat % nbx) * 256;

    // staging: lane l of segment rg loads global (row = rg*16 + (l>>2),
    // k = kel) so the linear LDS write (lane*16) lands st_16x32-swizzled.
    const int kel = ((((lane >> 1) ^ (lane >> 5)) & 1) << 4) + ((lane & 1) << 3);
    const __bf16* sA = A + (blockM + (size_t)(lane >> 2)) * lda + kel;
    const __bf16* sB = Bt + (blockN + (size_t)(lane >> 2)) * ldb + kel;

    // swizzled per-lane read offset within a granule subtile (bytes):
    // row r16 = lane&15, chunk g = lane>>4, XOR 32 for rows 8..15.
    const int ldsOff = (lane & 15) * 64 + (((lane >> 4) * 16) ^ (((lane >> 3) & 1) << 5));
    const int aOff = wm * 8192 + ldsOff;   // wave's A rowgroup base (wm*8 subtiles)
    const int bOff = wn * 4096 + ldsOff;   // wave's B rowgroup base (wn*4 subtiles)

#define STAGE_A(t, khc)                                                                   \
    do {                                                                                  \
        const int _k = (t) * 64 + (khc) * 32;                                             \
        gload16(sA + (size_t)(wave * 32) * lda + _k,                                      \
                &lds[(t) & 1][(khc)][wave * 1024]);                                       \
        gload16(sA + (size_t)(wave * 32 + 16) * lda + _k,                                 \
                &lds[(t) & 1][(khc)][wave * 1024 + 512]);                                 \
    } while (0)
#define STAGE_B(t, khc)                                                                   \
    do {                                                                                  \
        const int _k = (t) * 64 + (khc) * 32;                                             \
        gload16(sB + (size_t)(wave * 32) * ldb + _k,                                      \
                &lds[(t) & 1][2 + (khc)][wave * 1024]);                                   \
        gload16(sB + (size_t)(wave * 32 + 16) * ldb + _k,                                 \
                &lds[(t) & 1][2 + (khc)][wave * 1024 + 512]);                             \
    } while (0)

    f32x4 acc[8][4] = {};

    // prologue: tile 0 complete + tile 1's {B_k0, B_k1, A_k0}. 14 loads;
    // vmcnt(6) retains the 3 tile-1 granules in flight.
    STAGE_A(0, 0); STAGE_B(0, 0); STAGE_A(0, 1); STAGE_B(0, 1);
    STAGE_B(1, 0); STAGE_B(1, 1); STAGE_A(1, 0);
    asm volatile("s_waitcnt vmcnt(6)" ::: "memory");
    asm volatile("s_barrier" ::: "memory");

#pragma unroll 2
    for (int T = 0; T < NT; ++T) {
        const int b = T & 1;
        const char* Ag0 = (const char*)&lds[b][0][0];
        const char* Ag1 = (const char*)&lds[b][1][0];
        const char* Bg0 = (const char*)&lds[b][2][0];
        const char* Bg1 = (const char*)&lds[b][3][0];
        bf16x8 a0[4], a1[4], a2[4], a3[4], b0[4], b1[4];

        // ---- p0: issue all lo reads; stage A_k1(T+1); gate a0/b0; MFMA ----
#pragma unroll
        for (int mi = 0; mi < 4; ++mi) a0[mi] = *(const bf16x8*)(Ag0 + aOff + mi * 1024);
#pragma unroll
        for (int ni = 0; ni < 4; ++ni) b0[ni] = *(const bf16x8*)(Bg0 + bOff + ni * 1024);
#pragma unroll
        for (int mi = 0; mi < 4; ++mi) a1[mi] = *(const bf16x8*)(Ag1 + aOff + mi * 1024);
#pragma unroll
        for (int ni = 0; ni < 4; ++ni) b1[ni] = *(const bf16x8*)(Bg1 + bOff + ni * 1024);
        if (T + 1 < NT) STAGE_A(T + 1, 1);
        asm volatile("s_waitcnt lgkmcnt(8)" ::: "memory");
        __builtin_amdgcn_sched_barrier(0);
        __builtin_amdgcn_s_setprio(1);
#pragma unroll
        for (int mi = 0; mi < 4; ++mi)
#pragma unroll
            for (int ni = 0; ni < 4; ++ni)
                acc[mi][ni] = __builtin_amdgcn_mfma_f32_16x16x32_bf16(
                    a0[mi], b0[ni], acc[mi][ni], 0, 0, 0);
        __builtin_amdgcn_sched_barrier(0);
        __builtin_amdgcn_s_setprio(0);
        asm volatile("s_barrier" ::: "memory");

        // ---- p1: issue hi reads; stage B_k0(T+2); gate a1/b1; MFMA ----
#pragma unroll
        for (int mi = 0; mi < 4; ++mi)
            a2[mi] = *(const bf16x8*)(Ag0 + aOff + 4096 + mi * 1024);
#pragma unroll
        for (int mi = 0; mi < 4; ++mi)
            a3[mi] = *(const bf16x8*)(Ag1 + aOff + 4096 + mi * 1024);
        if (T + 2 < NT) STAGE_B(T + 2, 0);
        asm volatile("s_waitcnt lgkmcnt(8)" ::: "memory");
        __builtin_amdgcn_sched_barrier(0);
        __builtin_amdgcn_s_setprio(1);
#pragma unroll
        for (int mi = 0; mi < 4; ++mi)
#pragma unroll
            for (int ni = 0; ni < 4; ++ni)
                acc[mi][ni] = __builtin_amdgcn_mfma_f32_16x16x32_bf16(
                    a1[mi], b1[ni], acc[mi][ni], 0, 0, 0);
        __builtin_amdgcn_sched_barrier(0);
        __builtin_amdgcn_s_setprio(0);
        asm volatile("s_barrier" ::: "memory");

        // ---- p2: stage B_k1(T+2); gate a2; MFMA (b0 held in regs) ----
        if (T + 2 < NT) STAGE_B(T + 2, 1);
        asm volatile("s_waitcnt lgkmcnt(4)" ::: "memory");
        __builtin_amdgcn_sched_barrier(0);
        __builtin_amdgcn_s_setprio(1);
#pragma unroll
        for (int mi = 0; mi < 4; ++mi)
#pragma unroll
            for (int ni = 0; ni < 4; ++ni)
                acc[4 + mi][ni] = __builtin_amdgcn_mfma_f32_16x16x32_bf16(
                    a2[mi], b0[ni], acc[4 + mi][ni], 0, 0, 0);
        __builtin_amdgcn_sched_barrier(0);
        __builtin_amdgcn_s_setprio(0);
        asm volatile("s_barrier" ::: "memory");

        // ---- p3: stage A_k0(T+2); gate a3; MFMA (b1 held); counted vmcnt ----
        if (T + 2 < NT) STAGE_A(T + 2, 0);
        asm volatile("s_waitcnt lgkmcnt(0)" ::: "memory");
        __builtin_amdgcn_sched_barrier(0);
        __builtin_amdgcn_s_setprio(1);
#pragma unroll
        for (int mi = 0; mi < 4; ++mi)
#pragma unroll
            for (int ni = 0; ni < 4; ++ni)
                acc[4 + mi][ni] = __builtin_amdgcn_mfma_f32_16x16x32_bf16(
                    a3[mi], b1[ni], acc[4 + mi][ni], 0, 0, 0);
        __builtin_amdgcn_sched_barrier(0);
        __builtin_amdgcn_s_setprio(0);
        if (T + 2 < NT) asm volatile("s_waitcnt vmcnt(6)" ::: "memory");
        else            asm volatile("s_waitcnt vmcnt(0)" ::: "memory");
        asm volatile("s_barrier" ::: "memory");
    }
#undef STAGE_A
#undef STAGE_B

    // epilogue: C/D layout col = lane&15, row = (lane>>4)*4 + reg
    const int rEp = (lane >> 4) * 4;
    const int cEp = lane & 15;
#pragma unroll
    for (int mi = 0; mi < 8; ++mi) {
        const size_t row0 = blockM + wm * 128 + mi * 16 + rEp;
#pragma unroll
        for (int ni = 0; ni < 4; ++ni) {
            const size_t col = blockN + wn * 64 + ni * 16 + cEp;
#pragma unroll
            for (int r = 0; r < 4; ++r)
                C[(row0 + r) * (size_t)ldc + col] = (OutT)acc[mi][ni][r];
        }
    }
}

// ------------------------------------------------------------------
// Per-token attention. QKV rows: [q(2048) | k(2048) | v(2048)], bf16.
// One wave per token. scores = q @ k^T via 4 MFMAs (16x16x128), scores->LDS,
// o = scores @ v on VALU (fp32 acc). O written bf16 to COMPACT buffer Ob
// (lda = 2048) for the output GEMM's A-side locality.
// ------------------------------------------------------------------
__global__ __launch_bounds__(256) void attn_kernel(const __bf16* __restrict__ qkv,
                                                   __bf16* __restrict__ Ob) {
    __shared__ float sc[4][16][17];   // +1 pad
    const int tid = threadIdx.x;
    const int wave = tid >> 6;
    const int lane = tid & 63;
    const int t = lane & 15;
    const int quad = lane >> 4;
    const size_t token = (size_t)blockIdx.x * 4 + wave;
    const __bf16* row = qkv + token * QKVW;
    __bf16* orow = Ob + token * DD;

    // scores: A = q (M=16 heads x K=128), B-frag = k[n=t][k-dim] (contiguous)
    f32x4 s = (f32x4){0.f, 0.f, 0.f, 0.f};
#pragma unroll
    for (int ks = 0; ks < 4; ++ks) {
        bf16x8 a = *reinterpret_cast<const bf16x8*>(row + t * DK + ks * 32 + quad * 8);
        bf16x8 b = *reinterpret_cast<const bf16x8*>(row + DD + t * DK + ks * 32 + quad * 8);
        s = __builtin_amdgcn_mfma_f32_16x16x32_bf16(a, b, s, 0, 0, 0);
    }
#pragma unroll
    for (int i = 0; i < 4; ++i) sc[wave][quad * 4 + i][t] = s[i];  // s[h=quad*4+i][j=t]
    __syncthreads();

    // o[h][d] = sum_j s[h][j] * v[j][d]; lane covers heads {quad,quad+4,quad+8,quad+12},
    // d = t*8 .. t*8+7
    const int d0 = t * 8;
    float oa[4][8];
#pragma unroll
    for (int i = 0; i < 4; ++i)
#pragma unroll
        for (int e = 0; e < 8; ++e) oa[i][e] = 0.f;

#pragma unroll
    for (int j = 0; j < 16; ++j) {
        bf16x8 v8 = *reinterpret_cast<const bf16x8*>(row + 2 * DD + j * DK + d0);
        float vf[8];
#pragma unroll
        for (int e = 0; e < 8; ++e) vf[e] = (float)v8[e];
#pragma unroll
        for (int i = 0; i < 4; ++i) {
            const float sj = sc[wave][quad + 4 * i][j];
#pragma unroll
            for (int e = 0; e < 8; ++e) oa[i][e] += sj * vf[e];
        }
    }
#pragma unroll
    for (int i = 0; i < 4; ++i) {
        bf16x8 o8;
#pragma unroll
        for (int e = 0; e < 8; ++e) o8[e] = (__bf16)oa[i][e];
        *reinterpret_cast<bf16x8*>(orow + (quad + 4 * i) * DK + d0) = o8;
    }
}

// ------------------------------------------------------------------
extern "C" void kernel_launch(void* const* d_in, const int* in_sizes, int n_in,
                              void* d_out, int out_size, void* d_ws, size_t ws_size,
                              hipStream_t stream) {
    const float* X  = (const float*)d_in[0];
    const float* Wq = (const float*)d_in[1];
    const float* Wk = (const float*)d_in[2];
    const float* Wv = (const float*)d_in[3];
    const float* Wo = (const float*)d_in[4];
    float* out = (float*)d_out;

    // workspace layout (bf16): [Wcat_t 3*D*D][Wo_t D*D][Xb M*D][QKV M*3D] = 302 MB
    // Xb doubles as the attention-output buffer Ob (Xb dead after QKV GEMM).
    char* ws = (char*)d_ws;
    __bf16* Wcat = (__bf16*)ws;
    __bf16* Wo_t = (__bf16*)(ws + (size_t)3 * DD * DD * 2);
    __bf16* Xb   = (__bf16*)(ws + (size_t)4 * DD * DD * 2);
    __bf16* QKV  = (__bf16*)(ws + (size_t)4 * DD * DD * 2 + (size_t)MTOK * DD * 2);
    __bf16* Ob   = Xb;

    // 1) X -> bf16
    const int n4 = MTOK * DD / 4;
    xconv_kernel<<<(n4 + 255) / 256, 256, 0, stream>>>(X, Xb, n4);

    // 2) weights -> bf16, transposed to (N, K)
    wconv_kernel<<<dim3(DD / 32, DD / 32, 4), dim3(32, 8), 0, stream>>>(
        Wq, Wk, Wv, Wo, Wcat, Wo_t);

    // 3) QKV = Xb @ [Wq|Wk|Wv]  (M=16384, N=6144, K=2048), bf16 out
    gemm256<__bf16><<<dim3(QKVW / 256, MTOK / 256), 512, 0, stream>>>(
        Xb, DD, Wcat, DD, QKV, QKVW, DD);

    // 4) per-token attention -> compact Ob (overwrites Xb region)
    attn_kernel<<<MTOK / 4, 256, 0, stream>>>(QKV, Ob);

    // 5) out = Ob @ Wo  (M=16384, N=2048, K=2048), fp32 out
    gemm256<float><<<dim3(DD / 256, MTOK / 256), 512, 0, stream>>>(
        Ob, DD, Wo_t, DD, out, DD, DD);
}